// Round 6
// baseline (790.522 us; speedup 1.0000x reference)
//
#include <hip/hip_runtime.h>
#include <math.h>

#define NDIM 128

// One block per batch, 256 threads: thread (row = tid>>1, half = tid&1).
//
// Rounds 1-4 lesson: hipcc ALWAYS rematerializes invariant global loads
// instead of keeping a 64-float Q tile live (VGPR stuck at 56 across four
// structures) -> per-matvec Q re-reads from L2 were the bottleneck.
// Fix: allocator-proof residency. Inner-CG Q lives in LDS as PACKED fp16
// (32 KB/block, XOR-swizzled 16B groups; each thread reads only what it
// wrote -> no barriers needed for s_Q). Matvec = 16 ds_read_b128 + 32
// v_dot2_f32_f16. Outer Newton residual u = Qx - r/x stays fp32, re-read
// from global Q (~6x per block, L2/L3-cheap) -- endpoint accuracy is set
// by fp32 u + the lk<1e-5 exit, fp16 only perturbs the inner solve (~1%
// dk error, within the inexact-Newton forcing tol 3e-3).
//
// fp16 range safety: per-Newton scaling sigma = 1/max|u| (one extra fused
// reduction), per-CG-iter republish scale gamma = rsqrt(rz) keeps published
// vectors O(0.1-1) (normal fp16) through the whole solve.
//
// Round-5 compile fix: cvt_pkrtz returns __fp16 ext_vector_type(2) -- h2_t
// must be __fp16-based (not _Float16).

typedef __fp16 h2_t __attribute__((ext_vector_type(2)));
union U32H2 { unsigned int u; h2_t h; };

#if __has_builtin(__builtin_amdgcn_fdot2)
#define FDOT2(a, b, c) __builtin_amdgcn_fdot2((a), (b), (c), false)
#else
#define FDOT2(a, b, c) fmaf((float)(a).x, (float)(b).x, fmaf((float)(a).y, (float)(b).y, (c)))
#endif

// 16-byte-group swizzle: group g (0..15) within a 256B row, XOR row&15.
#define SWZ(r, g) ((((g) ^ ((r) & 15)) << 2))

__global__ __launch_bounds__(256, 4)
void rpth_kernel(const float* __restrict__ Q,
                 const float* __restrict__ R,
                 float* __restrict__ out)
{
    const int b    = blockIdx.x;
    const int tid  = threadIdx.x;
    const int row  = tid >> 1;
    const int half = tid & 1;
    const int lane = tid & 63;
    const int wv   = tid >> 6;          // 0..3

    __shared__ __align__(16) unsigned int s_Q[NDIM * 64]; // fp16x2 Q, swizzled (32 KB)
    __shared__ __align__(16) unsigned int s_vh[64];       // packed half2 CG vector
    __shared__ __align__(16) float s_vec[NDIM];           // fp32 vector (outer matvec)
    __shared__ float s_red[8];

    const size_t qbase = (size_t)b * (NDIM * NDIM);
    const float* qrow  = Q + qbase + (size_t)row * NDIM + half * 64;

    // ---- stage packed fp16 Q into LDS (each thread writes ONLY its own slots) ----
#pragma unroll
    for (int j = 0; j < 8; ++j) {
        const float4 a  = ((const float4*)qrow)[2 * j];
        const float4 bq = ((const float4*)qrow)[2 * j + 1];
        U32H2 w0, w1, w2, w3;
        w0.h = __builtin_amdgcn_cvt_pkrtz(a.x,  a.y);
        w1.h = __builtin_amdgcn_cvt_pkrtz(a.z,  a.w);
        w2.h = __builtin_amdgcn_cvt_pkrtz(bq.x, bq.y);
        w3.h = __builtin_amdgcn_cvt_pkrtz(bq.z, bq.w);
        const int g = half * 8 + j;
        *(uint4*)&s_Q[row * 64 + SWZ(row, g)] = make_uint4(w0.u, w1.u, w2.u, w3.u);
    }

    const float qd = Q[qbase + (size_t)row * NDIM + row];
    const float rv = fabsf(R[b * NDIM + row]);

    float xv = rv / sqrtf(qd);          // x0 = ORTHANT * r / sqrt(diag(Q))
    const float FLc = 0.36286771f;      // 0.95*(3-sqrt(5))/2
    float lk = FLc + 1.0f;

    for (int it = 0; it < 10; ++it) {
        if (half == 0) s_vec[row] = xv;
        __syncthreads();                                   // (X)

        // ---- outer fp32 matvec: qx = (Q x)[row], Q from global ----
        float qx;
        {
            const float4* sv4 = (const float4*)(s_vec + half * 64);
            const float4* gq  = (const float4*)qrow;
            float a0 = 0.f, a1 = 0.f, a2 = 0.f, a3 = 0.f;
#pragma unroll
            for (int j = 0; j < 4; ++j) {
                const float4 q0 = gq[4*j+0], q1 = gq[4*j+1], q2 = gq[4*j+2], q3 = gq[4*j+3];
                const float4 v0 = sv4[4*j+0], v1 = sv4[4*j+1], v2 = sv4[4*j+2], v3 = sv4[4*j+3];
                a0 = fmaf(q0.x,v0.x,a0); a0 = fmaf(q0.y,v0.y,a0); a0 = fmaf(q0.z,v0.z,a0); a0 = fmaf(q0.w,v0.w,a0);
                a1 = fmaf(q1.x,v1.x,a1); a1 = fmaf(q1.y,v1.y,a1); a1 = fmaf(q1.z,v1.z,a1); a1 = fmaf(q1.w,v1.w,a1);
                a2 = fmaf(q2.x,v2.x,a2); a2 = fmaf(q2.y,v2.y,a2); a2 = fmaf(q2.z,v2.z,a2); a2 = fmaf(q2.w,v2.w,a2);
                a3 = fmaf(q3.x,v3.x,a3); a3 = fmaf(q3.y,v3.y,a3); a3 = fmaf(q3.z,v3.z,a3); a3 = fmaf(q3.w,v3.w,a3);
            }
            float acc = (a0 + a1) + (a2 + a3);
            acc += __shfl_xor(acc, 1);
            qx = acc;
        }
        const float rx     = rv / xv;
        const float u      = qx - rx;                      // u = Qx - r/x (fp32)
        const float extra  = rx / xv;                      // r/x^2
        const float inv_hd = 1.0f / (qd + extra);          // Jacobi precond

        // ---- sigma = 1/max|u| so the scaled system is O(1) in fp16 ----
        float um = fabsf(u);
#pragma unroll
        for (int off = 32; off >= 2; off >>= 1) um = fmaxf(um, __shfl_xor(um, off));
        if (lane == 0) s_red[wv] = um;
        __syncthreads();                                   // (U)
        const float umax  = fmaxf(fmaxf(s_red[0], s_red[1]), fmaxf(s_red[2], s_red[3]));
        const float sigma = 1.0f / fmaxf(umax, 1e-30f);

        // ---- Chronopoulos-Gear PCG on h = Q_h + diag(extra), scaled RHS ----
        float res = u * sigma;
        float z   = res * inv_hd;
        float dk = 0.f, p = 0.f, sAp = 0.f;
        float alpha = 1.f, rz_prev = 1.f, rz0 = 0.f;
        float invgam = 1.0f;                               // published vhat = z * gamma
        {
            const float zp = __shfl_xor(z, 2);
            if ((tid & 3) == 0) {
                U32H2 wp; wp.h = __builtin_amdgcn_cvt_pkrtz(z, zp);
                s_vh[tid >> 2] = wp.u;
            }
        }

        for (int cg = 0; cg < 16; ++cg) {
            __syncthreads();                               // (A) vhat visible
            float acc = 0.0f;
#pragma unroll
            for (int j = 0; j < 8; ++j) {
                const int g = half * 8 + j;
                const uint4 qw = *(const uint4*)&s_Q[row * 64 + SWZ(row, g)];
                const uint4 vw = *(const uint4*)&s_vh[half * 32 + 4 * j];
                U32H2 qa, qb, qc, qe, va, vb, vc, ve;
                qa.u = qw.x; qb.u = qw.y; qc.u = qw.z; qe.u = qw.w;
                va.u = vw.x; vb.u = vw.y; vc.u = vw.z; ve.u = vw.w;
                acc = FDOT2(qa.h, va.h, acc);
                acc = FDOT2(qb.h, vb.h, acc);
                acc = FDOT2(qc.h, vc.h, acc);
                acc = FDOT2(qe.h, ve.h, acc);
            }
            acc += __shfl_xor(acc, 1);                     // combine halves
            const float w = fmaf(extra, z, acc * invgam);  // w = h z (fp32 scale restored)

            float pr = res * z;                            // fused dots (one copy/row
            float pd = z * w;                              //  via parity reduction)
#pragma unroll
            for (int off = 32; off >= 2; off >>= 1) {
                pr += __shfl_xor(pr, off);
                pd += __shfl_xor(pd, off);
            }
            if (lane == 0) { s_red[wv] = pr; s_red[4 + wv] = pd; }
            __syncthreads();                               // (B)
            const float rz    = (s_red[0] + s_red[1]) + (s_red[2] + s_red[3]);
            const float delta = (s_red[4] + s_red[5]) + (s_red[6] + s_red[7]);
            if (cg == 0) { rz0 = rz; if (rz0 <= 1e-30f) break; }
            else if (rz <= 1e-5f * rz0 || rz <= 1e-32f) break;   // loose tol
            const float beta = (cg == 0) ? 0.0f : rz / rz_prev;
            const float pAp  = delta - beta * rz / alpha;
            alpha = rz / pAp;
            p   = fmaf(beta, p, z);
            sAp = fmaf(beta, sAp, w);                      // sAp = h p (recurrence)
            dk  = fmaf( alpha, p,   dk);
            res = fmaf(-alpha, sAp, res);
            z   = res * inv_hd;
            rz_prev = rz;
            // republish vhat = z * gamma, gamma = rsqrt(rz) keeps fp16 well-scaled
            const float gam = rsqrtf(rz);
            invgam = sqrtf(rz);
            {
                const float vhat = z * gam;
                const float vp   = __shfl_xor(vhat, 2);
                if ((tid & 3) == 0) {
                    U32H2 wp; wp.h = __builtin_amdgcn_cvt_pkrtz(vhat, vp);
                    s_vh[tid >> 2] = wp.u;
                }
            }
        }
        const float dku = dk * umax;                       // unscale dk

        // ---- damping / bookkeeping (exact reference logic, fp32) ----
        __syncthreads();                                   // (C) s_red WAR guard
        {
            float gp = fabsf(dku / xv);
            float sp = dku * u;
#pragma unroll
            for (int off = 32; off >= 2; off >>= 1) {
                gp = fmaxf(gp, __shfl_xor(gp, off));
                sp += __shfl_xor(sp, off);
            }
            if (lane == 0) { s_red[wv] = gp; s_red[4 + wv] = sp; }
        }
        __syncthreads();                                   // (D)
        const float gm  = fmaxf(fmaxf(s_red[0], s_red[1]), fmaxf(s_red[2], s_red[3]));
        const float lkk = (s_red[4] + s_red[5]) + (s_red[6] + s_red[7]);
        const float gk     = (lk <= FLc) ? 0.0f : gm;
        const float lk_new = sqrtf(fmaxf(lkk, 0.0f));
        xv = xv - dku / (1.0f + gk);
        lk = lk_new;
        if (lk_new < 1e-5f) break;     // remaining reference motion <= 1e-5
    }

    // ---- normalize: x / (sum|x| + 1e-8) ----
    __syncthreads();
    {
        float sp = fabsf(xv);
#pragma unroll
        for (int off = 32; off >= 2; off >>= 1) sp += __shfl_xor(sp, off);
        if (lane == 0) s_red[wv] = sp;
    }
    __syncthreads();
    const float sabs = (s_red[0] + s_red[1]) + (s_red[2] + s_red[3]);
    if (half == 0) out[b * NDIM + row] = xv / (sabs + 1e-8f);
}

extern "C" void kernel_launch(void* const* d_in, const int* in_sizes, int n_in,
                              void* d_out, int out_size, void* d_ws, size_t ws_size,
                              hipStream_t stream) {
    const float* Q = (const float*)d_in[0];
    const float* R = (const float*)d_in[1];
    float* out     = (float*)d_out;
    const int B    = in_sizes[1] / NDIM;   // 4096
    rpth_kernel<<<dim3(B), dim3(256), 0, stream>>>(Q, R, out);
}

// Round 7
// 324.660 us; speedup vs baseline: 2.4349x; 2.4349x over previous
//
#include <hip/hip_runtime.h>
#include <math.h>

#define NDIM 128

// One block per batch, 256 threads: thread (row = tid>>1, half = tid&1) owns
// Q[b][row][half*64..+63] as PACKED fp16 hi/lo pairs in 64 uint VGPRs
// (H0..H7, L0..L7 as uint4). Residency trick: global fp32 -> cvt_pkrtz ->
// ds_write to a private LDS slot -> asm memory clobber -> ds_read back.
// The clobber kills store-to-load forwarding, and the backend never
// rematerializes ds_read across barriers -> values provably stay in VGPRs
// (rounds 1-4: global loads were always re-issued; round 6: global outer
// matvec re-reads were HBM-bound at 1.76 GB). Global Q is read EXACTLY once.
//
// Inner CG matvec: hi-only dot2 (rel err ~5e-4, inside the inexact-Newton
// forcing tol 3e-3). Outer Newton matvec: split hi/lo (Qh*xh + Qh*xl + Ql*xh,
// lo parts scaled x1024 at encode; rel err ~1e-6 => u is fp32-grade; dropped
// Ql*xl term ~1e-6). it=0's qx computed in fp32 during staging for free.

typedef __fp16 h2_t __attribute__((ext_vector_type(2)));
union U32H2 { unsigned int u; h2_t h; };

#if __has_builtin(__builtin_amdgcn_fdot2)
#define FDOT2(a, b, c) __builtin_amdgcn_fdot2((a), (b), (c), false)
#else
#define FDOT2(a, b, c) fmaf((float)(a).x, (float)(b).x, fmaf((float)(a).y, (float)(b).y, (c)))
#endif

#define DOTU4(QW, VW, ACC) { U32H2 _qa,_qb,_qc,_qd,_va,_vb,_vc,_vd;            \
    _qa.u=(QW).x; _qb.u=(QW).y; _qc.u=(QW).z; _qd.u=(QW).w;                    \
    _va.u=(VW).x; _vb.u=(VW).y; _vc.u=(VW).z; _vd.u=(VW).w;                    \
    ACC=FDOT2(_qa.h,_va.h,ACC); ACC=FDOT2(_qb.h,_vb.h,ACC);                    \
    ACC=FDOT2(_qc.h,_vc.h,ACC); ACC=FDOT2(_qd.h,_vd.h,ACC); }

__global__ __launch_bounds__(256, 3)
void rpth_kernel(const float* __restrict__ Q,
                 const float* __restrict__ R,
                 float* __restrict__ out)
{
    const int b    = blockIdx.x;
    const int tid  = threadIdx.x;
    const int row  = tid >> 1;
    const int half = tid & 1;
    const int lane = tid & 63;
    const int wv   = tid >> 6;          // 0..3

    __shared__ __align__(16) unsigned int s_stage[256 * 4]; // 4KB bounce buffer
    __shared__ __align__(16) unsigned int s_vh[64];         // packed fp16 CG vector
    __shared__ __align__(16) unsigned int s_xh[64];         // packed x hi
    __shared__ __align__(16) unsigned int s_xl[64];         // packed x lo (x1024)
    __shared__ __align__(16) float s_vec[NDIM];             // fp32 x0 (staging dot)
    __shared__ float s_red[8];

    const size_t qbase = (size_t)b * (NDIM * NDIM);
    const float* qrow  = Q + qbase + (size_t)row * NDIM + half * 64;
    const float qd = Q[qbase + (size_t)row * NDIM + row];
    const float rv = fabsf(R[b * NDIM + row]);
    float xv = rv / sqrtf(qd);          // x0 = ORTHANT * r / sqrt(diag(Q))

    if (half == 0) s_vec[row] = xv;
    __syncthreads();

    // ---- stage: global fp32 Q (ONCE) -> hi/lo fp16 in VGPRs; fp32 qx0 free ----
    uint4 H0,H1,H2,H3,H4,H5,H6,H7, L0,L1,L2,L3,L4,L5,L6,L7;
    float qx;
    {
        float a0=0.f,a1=0.f,a2=0.f,a3=0.f;
        const float4* sv4 = (const float4*)(s_vec + half * 64);
        unsigned int* slot = &s_stage[tid * 4];
#define STG(j, Hj, Lj) {                                                       \
        const float4 qa  = ((const float4*)qrow)[2*(j)];                       \
        const float4 qb2 = ((const float4*)qrow)[2*(j)+1];                     \
        const float4 va  = sv4[2*(j)], vb2 = sv4[2*(j)+1];                     \
        a0=fmaf(qa.x,va.x,a0);  a1=fmaf(qa.y,va.y,a1);                         \
        a2=fmaf(qa.z,va.z,a2);  a3=fmaf(qa.w,va.w,a3);                         \
        a0=fmaf(qb2.x,vb2.x,a0); a1=fmaf(qb2.y,vb2.y,a1);                      \
        a2=fmaf(qb2.z,vb2.z,a2); a3=fmaf(qb2.w,vb2.w,a3);                      \
        U32H2 h0,h1,h2,h3, l0,l1,l2,l3;                                        \
        h0.h = __builtin_amdgcn_cvt_pkrtz(qa.x,  qa.y);                        \
        h1.h = __builtin_amdgcn_cvt_pkrtz(qa.z,  qa.w);                        \
        h2.h = __builtin_amdgcn_cvt_pkrtz(qb2.x, qb2.y);                       \
        h3.h = __builtin_amdgcn_cvt_pkrtz(qb2.z, qb2.w);                       \
        l0.h = __builtin_amdgcn_cvt_pkrtz((qa.x -(float)h0.h.x)*1024.f,        \
                                          (qa.y -(float)h0.h.y)*1024.f);       \
        l1.h = __builtin_amdgcn_cvt_pkrtz((qa.z -(float)h1.h.x)*1024.f,        \
                                          (qa.w -(float)h1.h.y)*1024.f);       \
        l2.h = __builtin_amdgcn_cvt_pkrtz((qb2.x-(float)h2.h.x)*1024.f,        \
                                          (qb2.y-(float)h2.h.y)*1024.f);       \
        l3.h = __builtin_amdgcn_cvt_pkrtz((qb2.z-(float)h3.h.x)*1024.f,        \
                                          (qb2.w-(float)h3.h.y)*1024.f);       \
        *(uint4*)slot = make_uint4(h0.u,h1.u,h2.u,h3.u);                       \
        asm volatile("" ::: "memory");                                         \
        Hj = *(const uint4*)slot;                                              \
        asm volatile("" ::: "memory");                                         \
        *(uint4*)slot = make_uint4(l0.u,l1.u,l2.u,l3.u);                       \
        asm volatile("" ::: "memory");                                         \
        Lj = *(const uint4*)slot;                                              \
        asm volatile("" ::: "memory");                                         \
    }
        STG(0,H0,L0) STG(1,H1,L1) STG(2,H2,L2) STG(3,H3,L3)
        STG(4,H4,L4) STG(5,H5,L5) STG(6,H6,L6) STG(7,H7,L7)
#undef STG
        float acc = (a0+a1)+(a2+a3);
        acc += __shfl_xor(acc, 1);
        qx = acc;                                      // fp32 (Q x0)[row]
    }

    const float FLc = 0.36286771f;      // 0.95*(3-sqrt(5))/2
    float lk = FLc + 1.0f;

    for (int it = 0; it < 10; ++it) {
        if (it > 0) {
            __syncthreads();                           // x hi/lo published
            // ---- outer accurate matvec from registers: Qh*xh + (Qh*xl + Ql*xh)/1024
            float ah=0.f, am=0.f, al=0.f;
            const uint4* vhp = (const uint4*)&s_xh[half*32];
            const uint4* vlp = (const uint4*)&s_xl[half*32];
#define OCH(j,Hj,Lj) { const uint4 wh = vhp[j]; const uint4 wl = vlp[j];       \
            DOTU4(Hj, wh, ah) DOTU4(Hj, wl, am) DOTU4(Lj, wh, al) }
            OCH(0,H0,L0) OCH(1,H1,L1) OCH(2,H2,L2) OCH(3,H3,L3)
            OCH(4,H4,L4) OCH(5,H5,L5) OCH(6,H6,L6) OCH(7,H7,L7)
#undef OCH
            float acc = ah + (am + al) * 0.0009765625f;
            acc += __shfl_xor(acc, 1);
            qx = acc;
        }
        const float rx     = rv / xv;
        const float u      = qx - rx;                  // u = Qx - r/x
        const float extra  = rx / xv;                  // r/x^2
        const float inv_hd = 1.0f / (qd + extra);      // Jacobi precond

        // ---- sigma = 1/max|u| (fp16 scaling for the inner solve) ----
        float um = fabsf(u);
#pragma unroll
        for (int off = 32; off >= 2; off >>= 1) um = fmaxf(um, __shfl_xor(um, off));
        if (lane == 0) s_red[wv] = um;
        __syncthreads();                               // (U)
        const float umax  = fmaxf(fmaxf(s_red[0], s_red[1]), fmaxf(s_red[2], s_red[3]));
        const float sigma = 1.0f / fmaxf(umax, 1e-30f);

        // ---- Chronopoulos-Gear PCG on h = Qh + diag(extra), scaled RHS ----
        float res = u * sigma;
        float z   = res * inv_hd;
        float dk = 0.f, p = 0.f, sAp = 0.f;
        float alpha = 1.f, rz_prev = 1.f, rz0 = 0.f;
        float invgam = 1.0f;
        {
            const float zp = __shfl_xor(z, 2);
            if ((tid & 3) == 0) {
                U32H2 wp; wp.h = __builtin_amdgcn_cvt_pkrtz(z, zp);
                s_vh[tid >> 2] = wp.u;
            }
        }

        for (int cg = 0; cg < 16; ++cg) {
            __syncthreads();                           // (A) vhat visible
            float acc = 0.0f;
            const uint4* vp = (const uint4*)&s_vh[half*32];
#define ICH(j,Hj) { const uint4 wv4 = vp[j]; DOTU4(Hj, wv4, acc) }
            ICH(0,H0) ICH(1,H1) ICH(2,H2) ICH(3,H3)
            ICH(4,H4) ICH(5,H5) ICH(6,H6) ICH(7,H7)
#undef ICH
            acc += __shfl_xor(acc, 1);                 // combine halves
            const float w = fmaf(extra, z, acc * invgam);   // w = h z

            float pr = res * z;                        // fused dots (parity-deduped)
            float pd = z * w;
#pragma unroll
            for (int off = 32; off >= 2; off >>= 1) {
                pr += __shfl_xor(pr, off);
                pd += __shfl_xor(pd, off);
            }
            if (lane == 0) { s_red[wv] = pr; s_red[4 + wv] = pd; }
            __syncthreads();                           // (B)
            const float rz    = (s_red[0] + s_red[1]) + (s_red[2] + s_red[3]);
            const float delta = (s_red[4] + s_red[5]) + (s_red[6] + s_red[7]);
            if (cg == 0) { rz0 = rz; if (rz0 <= 1e-30f) break; }
            else if (rz <= 1e-5f * rz0 || rz <= 1e-32f) break;   // loose tol
            const float beta = (cg == 0) ? 0.0f : rz / rz_prev;
            const float pAp  = delta - beta * rz / alpha;
            alpha = rz / pAp;
            p   = fmaf(beta, p, z);
            sAp = fmaf(beta, sAp, w);                  // sAp = h p (recurrence)
            dk  = fmaf( alpha, p,   dk);
            res = fmaf(-alpha, sAp, res);
            z   = res * inv_hd;
            rz_prev = rz;
            const float gam = rsqrtf(rz);              // republish vhat = z*gamma
            invgam = sqrtf(rz);
            {
                const float vhat = z * gam;
                const float vo   = __shfl_xor(vhat, 2);
                if ((tid & 3) == 0) {
                    U32H2 wp; wp.h = __builtin_amdgcn_cvt_pkrtz(vhat, vo);
                    s_vh[tid >> 2] = wp.u;
                }
            }
        }
        const float dku = dk * umax;                   // unscale

        // ---- damping / bookkeeping (exact reference logic, fp32) ----
        __syncthreads();                               // (C) s_red WAR guard
        {
            float gp = fabsf(dku / xv);
            float sp = dku * u;
#pragma unroll
            for (int off = 32; off >= 2; off >>= 1) {
                gp = fmaxf(gp, __shfl_xor(gp, off));
                sp += __shfl_xor(sp, off);
            }
            if (lane == 0) { s_red[wv] = gp; s_red[4 + wv] = sp; }
        }
        __syncthreads();                               // (D)
        const float gm  = fmaxf(fmaxf(s_red[0], s_red[1]), fmaxf(s_red[2], s_red[3]));
        const float lkk = (s_red[4] + s_red[5]) + (s_red[6] + s_red[7]);
        const float gk     = (lk <= FLc) ? 0.0f : gm;
        const float lk_new = sqrtf(fmaxf(lkk, 0.0f));
        xv = xv - dku / (1.0f + gk);
        lk = lk_new;
        if (lk_new < 1e-5f) break;     // remaining reference motion <= 1e-5

        // ---- publish x as hi/lo fp16 for next outer matvec ----
        {
            U32H2 t; t.h = __builtin_amdgcn_cvt_pkrtz(xv, xv);
            const float hif = (float)t.h.x;
            const float lof = (xv - hif) * 1024.f;
            const float xo  = __shfl_xor(xv,  2);
            const float loo = __shfl_xor(lof, 2);
            if ((tid & 3) == 0) {
                U32H2 ph, pl;
                ph.h = __builtin_amdgcn_cvt_pkrtz(xv,  xo);
                pl.h = __builtin_amdgcn_cvt_pkrtz(lof, loo);
                s_xh[tid >> 2] = ph.u;
                s_xl[tid >> 2] = pl.u;
            }
        }
    }

    // ---- normalize: x / (sum|x| + 1e-8) ----
    __syncthreads();
    {
        float sp = fabsf(xv);
#pragma unroll
        for (int off = 32; off >= 2; off >>= 1) sp += __shfl_xor(sp, off);
        if (lane == 0) s_red[wv] = sp;
    }
    __syncthreads();
    const float sabs = (s_red[0] + s_red[1]) + (s_red[2] + s_red[3]);
    if (half == 0) out[b * NDIM + row] = xv / (sabs + 1e-8f);
}

extern "C" void kernel_launch(void* const* d_in, const int* in_sizes, int n_in,
                              void* d_out, int out_size, void* d_ws, size_t ws_size,
                              hipStream_t stream) {
    const float* Q = (const float*)d_in[0];
    const float* R = (const float*)d_in[1];
    float* out     = (float*)d_out;
    const int B    = in_sizes[1] / NDIM;   // 4096
    rpth_kernel<<<dim3(B), dim3(256), 0, stream>>>(Q, R, out);
}

// Round 9
// 190.566 us; speedup vs baseline: 4.1483x; 1.7037x over previous
//
#include <hip/hip_runtime.h>
#include <math.h>

#define NDIM 128

// ONE WAVE = ONE BATCH (64-thread blocks, grid = 4096). Lane owns rows
// r0=2*lane, r0+1 as 32 uint4 of packed fp16 (RTN) = 128 VGPRs. Row dots are
// fully lane-local (64 v_dot2 per row); ALL reductions are 6-level shfl_xor;
// ZERO __syncthreads in the kernel. The CG/matvec vector (128 vals = 64 u32)
// is published in LDS; within one wave ds_write -> ds_read is ordered by the
// in-order DS pipe (wave-synchronous), no barrier needed.
//
// Rounds 1-7 lessons: (a) hipcc remats invariant GLOBAL loads (VGPR stuck
// ~56) -> Q is transformed (cvt+pack chains are not remat-able) and pinned
// per-component ("+v" on uint4 aggregates does not compile -- round 8);
// (b) global outer-matvec re-reads are HBM-bound (round 6: 1.76 GB) -> Q
// global is read EXACTLY once; (c) barriers + 4-wave convoys ate ~40% at 58%
// VALUBusy -> wave-autonomous structure. __launch_bounds__(64,2): 256-VGPR
// budget so the ~180-reg peak cannot spill.
//
// Accuracy: Q hi-only fp16 RTN (rel ~1e-4; endpoint shift after the /sum|x|
// normalization ~1e-5 << 4.17e-4 threshold). x published hi+lo (22-bit) so
// the outer residual u is accurate. Inner: Jacobi-preconditioned
// Chronopoulos-Gear CG, tol rz<=1e-5*rz0 (inexact Newton), max 16 iters.
// Outer: exact reference lk/gk logic, per-batch exit lk<1e-5.

typedef __fp16 h2_t __attribute__((ext_vector_type(2)));
union U32H2 { unsigned int u; h2_t h; };

#if __has_builtin(__builtin_amdgcn_fdot2)
#define FDOT2(a,b,c) __builtin_amdgcn_fdot2((a),(b),(c),false)
#else
#define FDOT2(a,b,c) fmaf((float)(a).x,(float)(b).x, fmaf((float)(a).y,(float)(b).y,(c)))
#endif

__device__ __forceinline__ unsigned int pk_rtn(float x, float y) {
    U32H2 r; r.h.x = (__fp16)x; r.h.y = (__fp16)y; return r.u;   // RTN converts
}

#define DOT8(QW,VW,ACC) { U32H2 _qa,_qb,_qc,_qd,_va,_vb,_vc,_vd;               \
    _qa.u=(QW).x; _qb.u=(QW).y; _qc.u=(QW).z; _qd.u=(QW).w;                    \
    _va.u=(VW).x; _vb.u=(VW).y; _vc.u=(VW).z; _vd.u=(VW).w;                    \
    ACC=FDOT2(_qa.h,_va.h,ACC); ACC=FDOT2(_qb.h,_vb.h,ACC);                    \
    ACC=FDOT2(_qc.h,_vc.h,ACC); ACC=FDOT2(_qd.h,_vd.h,ACC); }

#define WSUM(v) { v += __shfl_xor(v,32); v += __shfl_xor(v,16);                \
                  v += __shfl_xor(v,8);  v += __shfl_xor(v,4);                 \
                  v += __shfl_xor(v,2);  v += __shfl_xor(v,1); }
#define WMAX(v) { v = fmaxf(v,__shfl_xor(v,32)); v = fmaxf(v,__shfl_xor(v,16));\
                  v = fmaxf(v,__shfl_xor(v,8));  v = fmaxf(v,__shfl_xor(v,4)); \
                  v = fmaxf(v,__shfl_xor(v,2));  v = fmaxf(v,__shfl_xor(v,1)); }

// Per-component pin: direct register ties (aggregate uint4 "+v" doesn't compile).
#define PIN4(V) asm volatile("" : "+v"(V.x), "+v"(V.y), "+v"(V.z), "+v"(V.w))

__global__ __launch_bounds__(64, 2)
void rpth_kernel(const float* __restrict__ Q,
                 const float* __restrict__ R,
                 float* __restrict__ out)
{
    const int b    = blockIdx.x;
    const int lane = threadIdx.x;            // 0..63
    const int r0   = 2 * lane;

    __shared__ __align__(16) unsigned int s_v [64];   // packed CG vector
    __shared__ __align__(16) unsigned int s_xh[64];   // packed x hi
    __shared__ __align__(16) unsigned int s_xl[64];   // packed x lo (x1024)

    const size_t qbase = (size_t)b * (NDIM * NDIM);
    const float* p0 = Q + qbase + (size_t)r0 * NDIM;
    const float* p1 = p0 + NDIM;

    // ---- stage: global fp32 Q (read ONCE) -> packed fp16 RTN in VGPRs ----
    uint4 A0,A1,A2,A3,A4,A5,A6,A7,A8,A9,A10,A11,A12,A13,A14,A15;   // row r0
    uint4 B0,B1,B2,B3,B4,B5,B6,B7,B8,B9,B10,B11,B12,B13,B14,B15;   // row r0+1
#define STG(c) {                                                               \
    const float4 _x0 = ((const float4*)p0)[2*(c)];                             \
    const float4 _x1 = ((const float4*)p0)[2*(c)+1];                           \
    const float4 _y0 = ((const float4*)p1)[2*(c)];                             \
    const float4 _y1 = ((const float4*)p1)[2*(c)+1];                           \
    A##c = make_uint4(pk_rtn(_x0.x,_x0.y), pk_rtn(_x0.z,_x0.w),                \
                      pk_rtn(_x1.x,_x1.y), pk_rtn(_x1.z,_x1.w));               \
    B##c = make_uint4(pk_rtn(_y0.x,_y0.y), pk_rtn(_y0.z,_y0.w),                \
                      pk_rtn(_y1.x,_y1.y), pk_rtn(_y1.z,_y1.w));               \
    PIN4(A##c); PIN4(B##c); }
    STG(0)  STG(1)  STG(2)  STG(3)  STG(4)  STG(5)  STG(6)  STG(7)
    STG(8)  STG(9)  STG(10) STG(11) STG(12) STG(13) STG(14) STG(15)
#undef STG

    const float qd0 = Q[qbase + (size_t)r0 * (NDIM + 1)];
    const float qd1 = Q[qbase + (size_t)(r0 + 1) * (NDIM + 1)];
    const float2 rr = ((const float2*)(R + (size_t)b * NDIM))[lane];
    const float rv0 = fabsf(rr.x), rv1 = fabsf(rr.y);

    float xv0 = rv0 / sqrtf(qd0);            // x0 = r / sqrt(diag Q)
    float xv1 = rv1 / sqrtf(qd1);

    const float FLc = 0.36286771f;           // 0.95*(3-sqrt(5))/2
    float lk = FLc + 1.0f;

#define PUBX() {                                                               \
    const float _h0 = (float)(__fp16)xv0, _h1 = (float)(__fp16)xv1;            \
    s_xh[lane] = pk_rtn(xv0, xv1);                                             \
    s_xl[lane] = pk_rtn((xv0 - _h0) * 1024.f, (xv1 - _h1) * 1024.f);           \
    asm volatile("" ::: "memory"); }
    PUBX();

    const uint4* vhp = (const uint4*)s_xh;
    const uint4* vlp = (const uint4*)s_xl;
    const uint4* vp  = (const uint4*)s_v;

    for (int it = 0; it < 10; ++it) {
        // ---- outer matvec qx = Qh*xh + Qh*xl/1024 (u accurate to ~1e-4) ----
        float ah0=0.f, ah1=0.f, al0=0.f, al1=0.f;
#define MVO(c) { const uint4 _Vh = vhp[c], _Vl = vlp[c];                       \
        DOT8(A##c,_Vh,ah0) DOT8(B##c,_Vh,ah1)                                  \
        DOT8(A##c,_Vl,al0) DOT8(B##c,_Vl,al1) }
        MVO(0)  MVO(1)  MVO(2)  MVO(3)  MVO(4)  MVO(5)  MVO(6)  MVO(7)
        MVO(8)  MVO(9)  MVO(10) MVO(11) MVO(12) MVO(13) MVO(14) MVO(15)
#undef MVO
        const float qx0 = fmaf(al0, 9.765625e-4f, ah0);
        const float qx1 = fmaf(al1, 9.765625e-4f, ah1);

        const float rx0 = rv0 / xv0,  rx1 = rv1 / xv1;
        const float u0  = qx0 - rx0,  u1  = qx1 - rx1;    // u = Qx - r/x
        const float ex0 = rx0 / xv0,  ex1 = rx1 / xv1;    // r/x^2
        const float ih0 = 1.0f / (qd0 + ex0);             // Jacobi precond
        const float ih1 = 1.0f / (qd1 + ex1);

        float umax = fmaxf(fabsf(u0), fabsf(u1));
        WMAX(umax);
        const float sigma = 1.0f / fmaxf(umax, 1e-30f);

        // ---- Chronopoulos-Gear PCG on h = Qh + diag(extra), scaled RHS ----
        float rs0 = u0 * sigma, rs1 = u1 * sigma;
        float z0  = rs0 * ih0,  z1  = rs1 * ih1;
        float dk0 = 0.f, dk1 = 0.f, pp0 = 0.f, pp1 = 0.f, sa0 = 0.f, sa1 = 0.f;
        float alpha = 1.f, rzp = 1.f, rz0v = 0.f, invgam = 1.f;
        s_v[lane] = pk_rtn(z0, z1);
        asm volatile("" ::: "memory");

        for (int cg = 0; cg < 16; ++cg) {
            float ac0a=0.f, ac0b=0.f, ac1a=0.f, ac1b=0.f;
#define MVI(c,X0,X1) { const uint4 _V = vp[c]; DOT8(A##c,_V,X0) DOT8(B##c,_V,X1) }
            MVI(0,ac0a,ac1a)  MVI(1,ac0b,ac1b)  MVI(2,ac0a,ac1a)  MVI(3,ac0b,ac1b)
            MVI(4,ac0a,ac1a)  MVI(5,ac0b,ac1b)  MVI(6,ac0a,ac1a)  MVI(7,ac0b,ac1b)
            MVI(8,ac0a,ac1a)  MVI(9,ac0b,ac1b)  MVI(10,ac0a,ac1a) MVI(11,ac0b,ac1b)
            MVI(12,ac0a,ac1a) MVI(13,ac0b,ac1b) MVI(14,ac0a,ac1a) MVI(15,ac0b,ac1b)
#undef MVI
            const float w0 = fmaf(ex0, z0, (ac0a + ac0b) * invgam);  // h z
            const float w1 = fmaf(ex1, z1, (ac1a + ac1b) * invgam);

            float pr = fmaf(rs0, z0, rs1 * z1);      // rz
            float pd = fmaf(z0,  w0, z1  * w1);      // z.hz
            WSUM(pr); WSUM(pd);
            if (cg == 0) { rz0v = pr; if (rz0v <= 1e-30f) break; }
            else if (pr <= 1e-5f * rz0v || pr <= 1e-32f) break;   // loose tol
            const float beta = (cg == 0) ? 0.0f : pr / rzp;
            const float pAp  = pd - beta * pr / alpha;
            alpha = pr / pAp;
            pp0 = fmaf(beta, pp0, z0);  pp1 = fmaf(beta, pp1, z1);
            sa0 = fmaf(beta, sa0, w0);  sa1 = fmaf(beta, sa1, w1);   // h p
            dk0 = fmaf(alpha, pp0, dk0); dk1 = fmaf(alpha, pp1, dk1);
            rs0 = fmaf(-alpha, sa0, rs0); rs1 = fmaf(-alpha, sa1, rs1);
            z0 = rs0 * ih0;  z1 = rs1 * ih1;
            rzp = pr;
            const float gam = rsqrtf(pr);            // republish vhat = z*gam
            invgam = sqrtf(pr);
            s_v[lane] = pk_rtn(z0 * gam, z1 * gam);
            asm volatile("" ::: "memory");
        }
        const float dku0 = dk0 * umax, dku1 = dk1 * umax;   // unscale

        // ---- damping / bookkeeping (exact reference logic, fp32) ----
        float gp = fmaxf(fabsf(dku0 / xv0), fabsf(dku1 / xv1));
        float sp = fmaf(dku0, u0, dku1 * u1);
        WMAX(gp); WSUM(sp);
        const float gk     = (lk <= FLc) ? 0.0f : gp;
        const float lk_new = sqrtf(fmaxf(sp, 0.0f));
        const float damp   = 1.0f / (1.0f + gk);
        xv0 -= dku0 * damp;
        xv1 -= dku1 * damp;
        lk = lk_new;
        if (lk_new < 1e-5f) break;     // remaining reference motion <= 1e-5
        PUBX();
    }

    // ---- normalize: x / (sum|x| + 1e-8) ----
    float sab = fabsf(xv0) + fabsf(xv1);
    WSUM(sab);
    const float inv = 1.0f / (sab + 1e-8f);
    ((float2*)(out + (size_t)b * NDIM))[lane] = make_float2(xv0 * inv, xv1 * inv);
}

extern "C" void kernel_launch(void* const* d_in, const int* in_sizes, int n_in,
                              void* d_out, int out_size, void* d_ws, size_t ws_size,
                              hipStream_t stream) {
    const float* Q = (const float*)d_in[0];
    const float* R = (const float*)d_in[1];
    float* out     = (float*)d_out;
    const int B    = in_sizes[1] / NDIM;   // 4096
    rpth_kernel<<<dim3(B), dim3(64), 0, stream>>>(Q, R, out);
}

// Round 10
// 177.368 us; speedup vs baseline: 4.4570x; 1.0744x over previous
//
#include <hip/hip_runtime.h>
#include <math.h>

#define NDIM 128

// ONE WAVE = ONE BATCH (64-thread blocks, grid = 4096). Lane owns rows
// r0=2*lane, r0+1 as 128 INDIVIDUALLY NAMED u32 scalars of packed fp16 (RTN).
// No arrays, no lambdas, no uint4 aggregates, no asm pins: every previous
// round's residency failure was an address-taken value (alloca -> scratch).
// These are pure SSA products of load->cvt_pkrtz chains: regalloc can't
// rematerialize a chain, and pressure (~175) < the launch_bounds(64,2) cap
// (256), so there is neither means nor motive to spill them.
//
// Row dots are fully lane-local (v_dot2); ALL reductions are 6-level
// shfl_xor; ZERO __syncthreads. The matvec vector (128 vals = 64 u32) is
// published in LDS; within one wave ds_write->ds_read is ordered by the
// in-order DS pipe + compiler lgkmcnt. Global Q is read EXACTLY once
// (round 6: outer-matvec global re-reads were HBM-bound at 1.76 GB).
//
// Accuracy: effective operator is Qh (fp16-RTN Q) -- endpoint shift after
// the /sum|x| normalization measured 1.2e-4 << 4.17e-4 threshold (round 9).
// x published hi+lo (22-bit) for the outer residual. Inner: Jacobi-
// preconditioned Chronopoulos-Gear CG, tol rz<=1e-5*rz0 (inexact Newton).
// Outer: exact reference lk/gk logic, per-batch exit lk<1e-5.

typedef __fp16 h2_t __attribute__((ext_vector_type(2)));
union U32H2 { unsigned int u; h2_t h; };

#if __has_builtin(__builtin_amdgcn_fdot2)
#define FDOT2(a,b,c) __builtin_amdgcn_fdot2((a),(b),(c),false)
#else
#define FDOT2(a,b,c) fmaf((float)(a).x,(float)(b).x, fmaf((float)(a).y,(float)(b).y,(c)))
#endif

__device__ __forceinline__ unsigned int pk_rtn(float x, float y) {
    U32H2 r; r.h.x = (__fp16)x; r.h.y = (__fp16)y; return r.u;   // RTN converts
}

// one packed-pair dot: ACC += dot(fp16x2(qu), fp16x2(vu))
#define DOTG(qu, vu, ACC) { U32H2 _q, _v; _q.u = (qu); _v.u = (vu);            \
    ACC = FDOT2(_q.h, _v.h, ACC); }

#define WSUM(v) { v += __shfl_xor(v,32); v += __shfl_xor(v,16);                \
                  v += __shfl_xor(v,8);  v += __shfl_xor(v,4);                 \
                  v += __shfl_xor(v,2);  v += __shfl_xor(v,1); }
#define WMAX(v) { v = fmaxf(v,__shfl_xor(v,32)); v = fmaxf(v,__shfl_xor(v,16));\
                  v = fmaxf(v,__shfl_xor(v,8));  v = fmaxf(v,__shfl_xor(v,4)); \
                  v = fmaxf(v,__shfl_xor(v,2));  v = fmaxf(v,__shfl_xor(v,1)); }

__global__ __launch_bounds__(64, 2)
void rpth_kernel(const float* __restrict__ Q,
                 const float* __restrict__ R,
                 float* __restrict__ out)
{
    const int b    = blockIdx.x;
    const int lane = threadIdx.x;            // 0..63
    const int r0   = 2 * lane;

    __shared__ __align__(16) unsigned int s_v [64];   // packed CG vector
    __shared__ __align__(16) unsigned int s_xh[64];   // packed x hi
    __shared__ __align__(16) unsigned int s_xl[64];   // packed x lo (x1024)

    const size_t qbase = (size_t)b * (NDIM * NDIM);
    const float* p0 = Q + qbase + (size_t)r0 * NDIM;
    const float* p1 = p0 + NDIM;

    // ---- 128 named u32 scalars: packed fp16 Q rows r0 (a*) and r0+1 (b*) ----
#define DECL(c) unsigned a##c##_0,a##c##_1,a##c##_2,a##c##_3,                  \
                         b##c##_0,b##c##_1,b##c##_2,b##c##_3;
    DECL(0)  DECL(1)  DECL(2)  DECL(3)  DECL(4)  DECL(5)  DECL(6)  DECL(7)
    DECL(8)  DECL(9)  DECL(10) DECL(11) DECL(12) DECL(13) DECL(14) DECL(15)
#undef DECL
#define STG(c) {                                                               \
    const float4 _x0 = ((const float4*)p0)[2*(c)];                             \
    const float4 _x1 = ((const float4*)p0)[2*(c)+1];                           \
    const float4 _y0 = ((const float4*)p1)[2*(c)];                             \
    const float4 _y1 = ((const float4*)p1)[2*(c)+1];                           \
    a##c##_0 = pk_rtn(_x0.x,_x0.y); a##c##_1 = pk_rtn(_x0.z,_x0.w);            \
    a##c##_2 = pk_rtn(_x1.x,_x1.y); a##c##_3 = pk_rtn(_x1.z,_x1.w);            \
    b##c##_0 = pk_rtn(_y0.x,_y0.y); b##c##_1 = pk_rtn(_y0.z,_y0.w);            \
    b##c##_2 = pk_rtn(_y1.x,_y1.y); b##c##_3 = pk_rtn(_y1.z,_y1.w); }
    STG(0)  STG(1)  STG(2)  STG(3)  STG(4)  STG(5)  STG(6)  STG(7)
    STG(8)  STG(9)  STG(10) STG(11) STG(12) STG(13) STG(14) STG(15)
#undef STG

    const float qd0 = Q[qbase + (size_t)r0 * (NDIM + 1)];
    const float qd1 = Q[qbase + (size_t)(r0 + 1) * (NDIM + 1)];
    const float2 rr = ((const float2*)(R + (size_t)b * NDIM))[lane];
    const float rv0 = fabsf(rr.x), rv1 = fabsf(rr.y);

    float xv0 = rv0 / sqrtf(qd0);            // x0 = r / sqrt(diag Q)
    float xv1 = rv1 / sqrtf(qd1);

    const float FLc = 0.36286771f;           // 0.95*(3-sqrt(5))/2
    float lk = FLc + 1.0f;

#define PUBX() {                                                               \
    const float _h0 = (float)(__fp16)xv0, _h1 = (float)(__fp16)xv1;            \
    s_xh[lane] = pk_rtn(xv0, xv1);                                             \
    s_xl[lane] = pk_rtn((xv0 - _h0) * 1024.f, (xv1 - _h1) * 1024.f);           \
    asm volatile("" ::: "memory"); }
    PUBX();

    const uint4* vhp = (const uint4*)s_xh;
    const uint4* vlp = (const uint4*)s_xl;
    const uint4* vp  = (const uint4*)s_v;

    for (int it = 0; it < 10; ++it) {
        // ---- outer matvec qx = Qh*xh + Qh*xl/1024 ----
        float ah0=0.f, ah1=0.f, al0=0.f, al1=0.f;
#define MVO(c) { const uint4 _Vh = vhp[c], _Vl = vlp[c];                       \
    DOTG(a##c##_0,_Vh.x,ah0) DOTG(a##c##_1,_Vh.y,ah0)                          \
    DOTG(a##c##_2,_Vh.z,ah0) DOTG(a##c##_3,_Vh.w,ah0)                          \
    DOTG(b##c##_0,_Vh.x,ah1) DOTG(b##c##_1,_Vh.y,ah1)                          \
    DOTG(b##c##_2,_Vh.z,ah1) DOTG(b##c##_3,_Vh.w,ah1)                          \
    DOTG(a##c##_0,_Vl.x,al0) DOTG(a##c##_1,_Vl.y,al0)                          \
    DOTG(a##c##_2,_Vl.z,al0) DOTG(a##c##_3,_Vl.w,al0)                          \
    DOTG(b##c##_0,_Vl.x,al1) DOTG(b##c##_1,_Vl.y,al1)                          \
    DOTG(b##c##_2,_Vl.z,al1) DOTG(b##c##_3,_Vl.w,al1) }
        MVO(0)  MVO(1)  MVO(2)  MVO(3)  MVO(4)  MVO(5)  MVO(6)  MVO(7)
        MVO(8)  MVO(9)  MVO(10) MVO(11) MVO(12) MVO(13) MVO(14) MVO(15)
#undef MVO
        const float qx0 = fmaf(al0, 9.765625e-4f, ah0);
        const float qx1 = fmaf(al1, 9.765625e-4f, ah1);

        const float rx0 = rv0 / xv0,  rx1 = rv1 / xv1;
        const float u0  = qx0 - rx0,  u1  = qx1 - rx1;    // u = Qx - r/x
        const float ex0 = rx0 / xv0,  ex1 = rx1 / xv1;    // r/x^2
        const float ih0 = 1.0f / (qd0 + ex0);             // Jacobi precond
        const float ih1 = 1.0f / (qd1 + ex1);

        float umax = fmaxf(fabsf(u0), fabsf(u1));
        WMAX(umax);
        const float sigma = 1.0f / fmaxf(umax, 1e-30f);

        // ---- Chronopoulos-Gear PCG on h = Qh + diag(extra), scaled RHS ----
        float rs0 = u0 * sigma, rs1 = u1 * sigma;
        float z0  = rs0 * ih0,  z1  = rs1 * ih1;
        float dk0 = 0.f, dk1 = 0.f, pp0 = 0.f, pp1 = 0.f, sa0 = 0.f, sa1 = 0.f;
        float alpha = 1.f, rzp = 1.f, rz0v = 0.f, invgam = 1.f;
        s_v[lane] = pk_rtn(z0, z1);
        asm volatile("" ::: "memory");

        for (int cg = 0; cg < 16; ++cg) {
            float ac0a=0.f, ac0b=0.f, ac1a=0.f, ac1b=0.f;
#define MVI(c,X0,X1) { const uint4 _V = vp[c];                                 \
    DOTG(a##c##_0,_V.x,X0) DOTG(a##c##_1,_V.y,X0)                              \
    DOTG(a##c##_2,_V.z,X0) DOTG(a##c##_3,_V.w,X0)                              \
    DOTG(b##c##_0,_V.x,X1) DOTG(b##c##_1,_V.y,X1)                              \
    DOTG(b##c##_2,_V.z,X1) DOTG(b##c##_3,_V.w,X1) }
            MVI(0,ac0a,ac1a)  MVI(1,ac0b,ac1b)  MVI(2,ac0a,ac1a)  MVI(3,ac0b,ac1b)
            MVI(4,ac0a,ac1a)  MVI(5,ac0b,ac1b)  MVI(6,ac0a,ac1a)  MVI(7,ac0b,ac1b)
            MVI(8,ac0a,ac1a)  MVI(9,ac0b,ac1b)  MVI(10,ac0a,ac1a) MVI(11,ac0b,ac1b)
            MVI(12,ac0a,ac1a) MVI(13,ac0b,ac1b) MVI(14,ac0a,ac1a) MVI(15,ac0b,ac1b)
#undef MVI
            const float w0 = fmaf(ex0, z0, (ac0a + ac0b) * invgam);  // h z
            const float w1 = fmaf(ex1, z1, (ac1a + ac1b) * invgam);

            float pr = fmaf(rs0, z0, rs1 * z1);      // rz
            float pd = fmaf(z0,  w0, z1  * w1);      // z.hz
            WSUM(pr); WSUM(pd);
            if (cg == 0) { rz0v = pr; if (rz0v <= 1e-30f) break; }
            else if (pr <= 1e-5f * rz0v || pr <= 1e-32f) break;   // loose tol
            const float beta = (cg == 0) ? 0.0f : pr / rzp;
            const float pAp  = pd - beta * pr / alpha;
            alpha = pr / pAp;
            pp0 = fmaf(beta, pp0, z0);  pp1 = fmaf(beta, pp1, z1);
            sa0 = fmaf(beta, sa0, w0);  sa1 = fmaf(beta, sa1, w1);   // h p
            dk0 = fmaf(alpha, pp0, dk0); dk1 = fmaf(alpha, pp1, dk1);
            rs0 = fmaf(-alpha, sa0, rs0); rs1 = fmaf(-alpha, sa1, rs1);
            z0 = rs0 * ih0;  z1 = rs1 * ih1;
            rzp = pr;
            const float gam = rsqrtf(pr);            // republish vhat = z*gam
            invgam = sqrtf(pr);
            s_v[lane] = pk_rtn(z0 * gam, z1 * gam);
            asm volatile("" ::: "memory");
        }
        const float dku0 = dk0 * umax, dku1 = dk1 * umax;   // unscale

        // ---- damping / bookkeeping (exact reference logic, fp32) ----
        float gp = fmaxf(fabsf(dku0 / xv0), fabsf(dku1 / xv1));
        float sp = fmaf(dku0, u0, dku1 * u1);
        WMAX(gp); WSUM(sp);
        const float gk     = (lk <= FLc) ? 0.0f : gp;
        const float lk_new = sqrtf(fmaxf(sp, 0.0f));
        const float damp   = 1.0f / (1.0f + gk);
        xv0 -= dku0 * damp;
        xv1 -= dku1 * damp;
        lk = lk_new;
        if (lk_new < 1e-5f) break;     // remaining reference motion <= 1e-5
        PUBX();
    }

    // ---- normalize: x / (sum|x| + 1e-8) ----
    float sab = fabsf(xv0) + fabsf(xv1);
    WSUM(sab);
    const float inv = 1.0f / (sab + 1e-8f);
    ((float2*)(out + (size_t)b * NDIM))[lane] = make_float2(xv0 * inv, xv1 * inv);
}

extern "C" void kernel_launch(void* const* d_in, const int* in_sizes, int n_in,
                              void* d_out, int out_size, void* d_ws, size_t ws_size,
                              hipStream_t stream) {
    const float* Q = (const float*)d_in[0];
    const float* R = (const float*)d_in[1];
    float* out     = (float*)d_out;
    const int B    = in_sizes[1] / NDIM;   // 4096
    rpth_kernel<<<dim3(B), dim3(64), 0, stream>>>(Q, R, out);
}